// Round 4
// baseline (54.498 us; speedup 1.0000x reference)
//
#include <hip/hip_runtime.h>

#define SL 10
#define NI 128

typedef float f32x4 __attribute__((ext_vector_type(4)));
typedef unsigned int u32;
typedef u32 u32x4 __attribute__((ext_vector_type(4)));
typedef _Float16 h8 __attribute__((ext_vector_type(8)));
typedef _Float16 h4 __attribute__((ext_vector_type(4)));

__device__ __forceinline__ f32x4 MFH(h8 a, h8 b, f32x4 c){
  return __builtin_amdgcn_mfma_f32_16x16x32_f16(a, b, c, 0, 0, 0);
}
__device__ __forceinline__ float sigf(float x){ return __fdividef(1.f, 1.f + __expf(-x)); }
__device__ __forceinline__ float tanhf2(float x){ return __fdividef(2.f, 1.f + __expf(-2.f*x)) - 1.f; }

__device__ __forceinline__ h8 to_h8(float4 a, float4 b){
  h8 r;
  r[0]=(_Float16)a.x; r[1]=(_Float16)a.y; r[2]=(_Float16)a.z; r[3]=(_Float16)a.w;
  r[4]=(_Float16)b.x; r[5]=(_Float16)b.y; r[6]=(_Float16)b.z; r[7]=(_Float16)b.w;
  return r;
}

__device__ __forceinline__ void ldx8(float4 (&b)[8], const float* p){
  #pragma unroll
  for(int ks=0;ks<4;ks++){
    b[2*ks]   = *(const float4*)(p + ks*32);
    b[2*ks+1] = *(const float4*)(p + ks*32 + 4);
  }
}
// load W_ih_b fragment group g (frags p=4g..4g+3) into buffer
__device__ __forceinline__ void ldw4(float4 (&b)[8], const float* Wb, int gb, int g, int lg){
  #pragma unroll
  for(int f=0;f<4;f++){
    const int p = g*4+f;
    const float* s = Wb + (gb + (p>>2)*4)*NI + (p&3)*32 + lg*8;
    b[2*f]   = *(const float4*)s;
    b[2*f+1] = *(const float4*)(s+4);
  }
}
__device__ __forceinline__ void cvt4(h8 (&bx)[4], const float4 (&b)[8]){
  #pragma unroll
  for(int ks=0;ks<4;ks++) bx[ks] = to_h8(b[2*ks], b[2*ks+1]);
}

// One wave (64 threads) per 16 batch rows, zero barriers, depth-2 global prefetch.
//   A = weights (gate-permuted rows: A-row lr, tile nt -> gate (lr&3)*20+(lr>>2)+nt*4),
//   B = x/h (col = batch row lr). C-reg i of lane (lr,lg) = gate type i of unit
//   nt*4+lg for batch col lr -> fp32 gate math fully in-register.
//   h exchange via 2KB wave-private LDS (stride 33), no s_barrier.
//   Pipeline: iter t converts x[t], issues x[t+2]; t=8/9 issue W_ih_b groups 0/1
//   into the freed buffers; epilogue rolls groups 2..4.
__global__ __launch_bounds__(64, 2) void bilstm_kernel(
    const float* __restrict__ x,
    const float* __restrict__ Wih_f, const float* __restrict__ Whh_f,
    const float* __restrict__ bih_f, const float* __restrict__ bhh_f,
    const float* __restrict__ Wih_b,
    const float* __restrict__ bih_b, const float* __restrict__ bhh_b,
    float* __restrict__ out)
{
  __shared__ u32 HB[16*33];   // [col lr][unit] = (h_hi16<<16)|h_lo16
  const int lane = threadIdx.x;
  const int lr = lane & 15;
  const int lg = lane >> 4;
  const long row = (long)blockIdx.x*16 + lr;
  const int gb = (lr&3)*20 + (lr>>2);

  for(int i=lane;i<16*33;i+=64) HB[i]=0;

  // ---- depth-2 x prefetch: t=0 -> b0, t=1 -> b1 ----
  float4 b0[8], b1[8];
  const float* xb = x + row*(long)(SL*NI) + lg*8;
  ldx8(b0, xb);
  ldx8(b1, xb + NI);

  // ---- W_ih_f fragments (f16), register-resident ----
  h8 WIH[20];
  #pragma unroll
  for(int p=0;p<20;p++){
    const int nt=p>>2, ks=p&3;
    const float* s = Wih_f + (gb+nt*4)*NI + ks*32 + lg*8;
    WIH[p] = to_h8(*(const float4*)s, *(const float4*)(s+4));
  }
  // ---- W_hh_f fragments (K=20 zero-padded to 32) ----
  h8 WHH[5];
  #pragma unroll
  for(int nt=0;nt<5;nt++){
    const float* s = Whh_f + (gb+nt*4)*20 + lg*8;
    float4 wa = {0.f,0.f,0.f,0.f}, wc = {0.f,0.f,0.f,0.f};
    if(lg<3) wa = *(const float4*)s;
    if(lg<2) wc = *(const float4*)(s+4);
    WHH[nt] = to_h8(wa, wc);
  }
  // ---- forward bias, packed f16 ----
  h4 bp[5];
  #pragma unroll
  for(int nt=0;nt<5;nt++)
    #pragma unroll
    for(int ty=0;ty<4;ty++)
      bp[nt][ty] = (_Float16)(bih_f[ty*20+nt*4+lg] + bhh_f[ty*20+nt*4+lg]);

  float cst[5]={0.f,0.f,0.f,0.f,0.f};
  h8 bx[4];
  f32x4 acc[5];

  #pragma unroll
  for(int t=0;t<SL;t++){
    // convert current x buffer (loads issued 2 iterations ago)
    if(t&1) cvt4(bx, b1); else cvt4(bx, b0);
    // refill the freed buffer: x[t+2], or W_ih_b groups at t=8/9
    if(t+2<SL){
      if(t&1) ldx8(b1, xb+(t+2)*NI); else ldx8(b0, xb+(t+2)*NI);
    } else if(t==8){
      ldw4(b0, Wih_b, gb, 0, lg);
    } else {
      ldw4(b1, Wih_b, gb, 1, lg);
    }
    // h_{t-1} read (wave-coherent LDS, no barrier)
    u32x4 hb0, hb1;
    if(t>0){
      const u32* hp = HB + lr*33 + lg*8;
      hb0=*(const u32x4*)hp; hb1=*(const u32x4*)(hp+4);
    }
    #pragma unroll
    for(int nt=0;nt<5;nt++){
      acc[nt][0]=(float)bp[nt][0]; acc[nt][1]=(float)bp[nt][1];
      acc[nt][2]=(float)bp[nt][2]; acc[nt][3]=(float)bp[nt][3];
    }
    // projection: 20 MFMAs
    #pragma unroll
    for(int ks=0;ks<4;ks++)
      #pragma unroll
      for(int nt=0;nt<5;nt++)
        acc[nt]=MFH(WIH[nt*4+ks], bx[ks], acc[nt]);
    // recurrence: 10 MFMAs (h 2-term f16)
    if(t>0){
      u32x4 hh, hl;
      hh[0]=(hb0[0]>>16)|(hb0[1]&0xffff0000u);
      hh[1]=(hb0[2]>>16)|(hb0[3]&0xffff0000u);
      hh[2]=(hb1[0]>>16)|(hb1[1]&0xffff0000u);
      hh[3]=(hb1[2]>>16)|(hb1[3]&0xffff0000u);
      hl[0]=(hb0[0]&0xffffu)|(hb0[1]<<16);
      hl[1]=(hb0[2]&0xffffu)|(hb0[3]<<16);
      hl[2]=(hb1[0]&0xffffu)|(hb1[1]<<16);
      hl[3]=(hb1[2]&0xffffu)|(hb1[3]<<16);
      h8 fh=__builtin_bit_cast(h8,hh), fl=__builtin_bit_cast(h8,hl);
      #pragma unroll
      for(int nt=0;nt<5;nt++){
        acc[nt]=MFH(WHH[nt], fh, acc[nt]);
        acc[nt]=MFH(WHH[nt], fl, acc[nt]);
      }
    }
    // in-register fp32 gate math
    #pragma unroll
    for(int nt=0;nt<5;nt++){
      float ig=sigf(acc[nt][0]);
      float fg=sigf(acc[nt][1]);
      float gg=tanhf2(acc[nt][2]);
      float og=sigf(acc[nt][3]);
      cst[nt]=fg*cst[nt]+ig*gg;
      float hv=og*tanhf2(cst[nt]);
      if(t==SL-1){
        out[row*40 + nt*4+lg] = hv;
      } else {
        _Float16 hh16=(_Float16)hv;
        _Float16 hl16=(_Float16)(hv-(float)hh16);
        HB[lr*33 + nt*4+lg] = ((u32)__builtin_bit_cast(unsigned short,hh16)<<16)
                              | (u32)__builtin_bit_cast(unsigned short,hl16);
      }
    }
  }

  // ---- backward direction: one step, h0=c0=0, bx still holds x[t=9] ----
  float bb[20];
  #pragma unroll
  for(int nt=0;nt<5;nt++)
    #pragma unroll
    for(int ty=0;ty<4;ty++)
      bb[nt*4+ty] = bih_b[ty*20+nt*4+lg] + bhh_b[ty*20+nt*4+lg];

  f32x4 a2[5];
  #pragma unroll
  for(int nt=0;nt<5;nt++){ f32x4 z={0.f,0.f,0.f,0.f}; a2[nt]=z; }

  h8 wb[4];
  #pragma unroll
  for(int g=0;g<5;g++){
    if(g&1) cvt4(wb, b1); else cvt4(wb, b0);       // group g (in flight)
    if(g+2<5){                                     // roll: issue group g+2
      if(g&1) ldw4(b1, Wih_b, gb, g+2, lg); else ldw4(b0, Wih_b, gb, g+2, lg);
    }
    #pragma unroll
    for(int ks=0;ks<4;ks++) a2[g]=MFH(wb[ks], bx[ks], a2[g]);
  }
  #pragma unroll
  for(int nt=0;nt<5;nt++){
    float ig=sigf(a2[nt][0]+bb[nt*4+0]);
    float gg=tanhf2(a2[nt][2]+bb[nt*4+2]);
    float og=sigf(a2[nt][3]+bb[nt*4+3]);
    out[row*40 + 20 + nt*4+lg] = og*tanhf2(ig*gg);  // c = i*g (f-gate hits c0=0)
  }
}

extern "C" void kernel_launch(void* const* d_in, const int* in_sizes, int n_in,
                              void* d_out, int out_size, void* d_ws, size_t ws_size,
                              hipStream_t stream) {
  const float* x     = (const float*)d_in[0];
  const float* Wih_f = (const float*)d_in[1];
  const float* Whh_f = (const float*)d_in[2];
  const float* bih_f = (const float*)d_in[3];
  const float* bhh_f = (const float*)d_in[4];
  const float* Wih_b = (const float*)d_in[5];
  // d_in[6] = W_hh_b: provably unused (hs_b[0] has h0 = 0)
  const float* bih_b = (const float*)d_in[7];
  const float* bhh_b = (const float*)d_in[8];
  float* out = (float*)d_out;
  bilstm_kernel<<<dim3(2048), dim3(64), 0, stream>>>(
      x, Wih_f, Whh_f, bih_f, bhh_f, Wih_b, bih_b, bhh_b, out);
}